// Round 1
// baseline (383.745 us; speedup 1.0000x reference)
//
#include <hip/hip_runtime.h>

#define S_LEN 4096
#define DHEAD 64
#define BQ    128      // Q rows per block
#define BK    64       // K/V rows per tile
#define WQ    32       // Q rows per wave
#define NWAVES 4
#define KPAD  72       // 64 + 8 halfs -> 144B row stride, 16B aligned, 2-way-max bank alias

typedef _Float16 half8 __attribute__((ext_vector_type(8)));
typedef float    f32x4 __attribute__((ext_vector_type(4)));

// ---------------------------------------------------------------------------
// Pass 1: is the mask anywhere nonzero?  (reads 67MB once; bench mask == 0)
// ---------------------------------------------------------------------------
__global__ void mask_flag_kernel(const float* __restrict__ mask, int* __restrict__ flag, long n4) {
    long i = (long)blockIdx.x * blockDim.x + threadIdx.x;
    long stride = (long)gridDim.x * blockDim.x;
    int nz = 0;
    const float4* m4 = (const float4*)mask;
    for (long j = i; j < n4; j += stride) {
        float4 v = m4[j];
        nz |= (v.x != 0.0f) | (v.y != 0.0f) | (v.z != 0.0f) | (v.w != 0.0f);
    }
    if (__any(nz)) {
        if ((threadIdx.x & 63) == 0) atomicOr(flag, 1);
    }
}

// ---------------------------------------------------------------------------
// Pass 2: flash attention, f16 MFMA, fp32 accumulate
//   grid = (S/BQ, B*H); block = 256 (4 waves); wave handles 32 Q rows
// MFMA 16x16x32 f16 layouts (learn_hip verified):
//   A: m = lane&15, k = (lane>>4)*8 + j   (j = 0..7, 8 halfs / 4 VGPRs)
//   B: n = lane&15, k = (lane>>4)*8 + j
//   C/D: col = lane&15, row = (lane>>4)*4 + reg
// ---------------------------------------------------------------------------
__global__ __launch_bounds__(256, 2) void attn_kernel(
    const float* __restrict__ Q, const float* __restrict__ K,
    const float* __restrict__ V, const int* __restrict__ dk,
    const float* __restrict__ mask, const int* __restrict__ maskflag,
    float* __restrict__ O)
{
    const int qt   = blockIdx.x;      // 0..31
    const int bh   = blockIdx.y;      // 0..15
    const int tid  = threadIdx.x;
    const int wave = tid >> 6;
    const int lane = tid & 63;
    const int l15  = lane & 15;
    const int quad = lane >> 4;

    const long base = (long)bh * S_LEN * DHEAD;
    const float* Qh = Q + base;
    const float* Kh = K + base;
    const float* Vh = V + base;
    float*       Oh = O + base;

    const int q0 = qt * BQ + wave * WQ;
    const float scale = rsqrtf((float)dk[0]);
    const bool use_mask = (maskflag[0] != 0);

    __shared__ __align__(16) _Float16 Kt[BK][KPAD];          // [k-row][d]
    __shared__ __align__(16) _Float16 Vt[DHEAD][KPAD];       // [d][k-row] (transposed)
    __shared__ __align__(16) _Float16 Pb[NWAVES][WQ][KPAD];  // per-wave P scratch

    // ---- load Q fragments once (A-operand layout), fp32 -> f16 ----
    half8 qf[2][2];   // [m-tile][k-chunk]
    #pragma unroll
    for (int mt = 0; mt < 2; ++mt) {
        #pragma unroll
        for (int kc = 0; kc < 2; ++kc) {
            const float4* src = (const float4*)(Qh + (long)(q0 + mt*16 + l15) * DHEAD + kc*32 + quad*8);
            float4 a = src[0], b = src[1];
            half8 h;
            h[0]=(_Float16)a.x; h[1]=(_Float16)a.y; h[2]=(_Float16)a.z; h[3]=(_Float16)a.w;
            h[4]=(_Float16)b.x; h[5]=(_Float16)b.y; h[6]=(_Float16)b.z; h[7]=(_Float16)b.w;
            qf[mt][kc] = h;
        }
    }

    f32x4 o[2][4];               // [m-tile][d-tile] accumulators, C/D layout
    float m_i[2][4], l_i[2][4];  // [m-tile][reg] per-row online-softmax state
    #pragma unroll
    for (int mt = 0; mt < 2; ++mt) {
        #pragma unroll
        for (int nt = 0; nt < 4; ++nt) o[mt][nt] = (f32x4){0.f, 0.f, 0.f, 0.f};
        #pragma unroll
        for (int r = 0; r < 4; ++r) { m_i[mt][r] = -INFINITY; l_i[mt][r] = 0.0f; }
    }

    for (int kt = 0; kt < S_LEN / BK; ++kt) {
        __syncthreads();   // previous tile fully consumed before overwrite
        // ---- stage K (row-major) and V (transposed) into LDS ----
        {
            const int r   = tid >> 2;   // 0..63: k-row within tile
            const int seg = tid & 3;    // 16-float segment of d
            const float4* k4 = (const float4*)(Kh + (long)(kt*BK + r) * DHEAD + seg*16);
            const float4* v4 = (const float4*)(Vh + (long)(kt*BK + r) * DHEAD + seg*16);
            float4 x0 = k4[0], x1 = k4[1], x2 = k4[2], x3 = k4[3];
            half8 h0, h1;
            h0[0]=(_Float16)x0.x; h0[1]=(_Float16)x0.y; h0[2]=(_Float16)x0.z; h0[3]=(_Float16)x0.w;
            h0[4]=(_Float16)x1.x; h0[5]=(_Float16)x1.y; h0[6]=(_Float16)x1.z; h0[7]=(_Float16)x1.w;
            h1[0]=(_Float16)x2.x; h1[1]=(_Float16)x2.y; h1[2]=(_Float16)x2.z; h1[3]=(_Float16)x2.w;
            h1[4]=(_Float16)x3.x; h1[5]=(_Float16)x3.y; h1[6]=(_Float16)x3.z; h1[7]=(_Float16)x3.w;
            *(half8*)&Kt[r][seg*16]     = h0;
            *(half8*)&Kt[r][seg*16 + 8] = h1;
            float4 y0 = v4[0], y1 = v4[1], y2 = v4[2], y3 = v4[3];
            float vv[16] = {y0.x,y0.y,y0.z,y0.w, y1.x,y1.y,y1.z,y1.w,
                            y2.x,y2.y,y2.z,y2.w, y3.x,y3.y,y3.z,y3.w};
            #pragma unroll
            for (int j = 0; j < 16; ++j) Vt[seg*16 + j][r] = (_Float16)vv[j];
        }
        __syncthreads();

        // ---- S = Q K^T (32 x BK), fp32 accumulate ----
        f32x4 s[2][4];
        #pragma unroll
        for (int mt = 0; mt < 2; ++mt)
            #pragma unroll
            for (int nt = 0; nt < 4; ++nt) s[mt][nt] = (f32x4){0.f,0.f,0.f,0.f};
        #pragma unroll
        for (int nt = 0; nt < 4; ++nt) {
            #pragma unroll
            for (int kc = 0; kc < 2; ++kc) {
                half8 bf = *(const half8*)&Kt[nt*16 + l15][kc*32 + quad*8];
                s[0][nt] = __builtin_amdgcn_mfma_f32_16x16x32_f16(qf[0][kc], bf, s[0][nt], 0, 0, 0);
                s[1][nt] = __builtin_amdgcn_mfma_f32_16x16x32_f16(qf[1][kc], bf, s[1][nt], 0, 0, 0);
            }
        }
        // scale (+ mask only if it is nonzero anywhere)
        #pragma unroll
        for (int mt = 0; mt < 2; ++mt)
            #pragma unroll
            for (int nt = 0; nt < 4; ++nt)
                #pragma unroll
                for (int r = 0; r < 4; ++r) s[mt][nt][r] *= scale;
        if (use_mask) {
            for (int mt = 0; mt < 2; ++mt)
                for (int nt = 0; nt < 4; ++nt)
                    for (int r = 0; r < 4; ++r) {
                        long row = q0 + mt*16 + quad*4 + r;
                        long col = (long)kt*BK + nt*16 + l15;
                        s[mt][nt][r] += -1e9f * mask[row * S_LEN + col];
                    }
        }

        // ---- online softmax per row (row lives on 16 lanes of one quad) ----
        #pragma unroll
        for (int mt = 0; mt < 2; ++mt) {
            #pragma unroll
            for (int r = 0; r < 4; ++r) {
                float mx = fmaxf(fmaxf(s[mt][0][r], s[mt][1][r]), fmaxf(s[mt][2][r], s[mt][3][r]));
                #pragma unroll
                for (int off = 1; off < 16; off <<= 1)
                    mx = fmaxf(mx, __shfl_xor(mx, off, 64));
                float mold = m_i[mt][r];
                float mnew = fmaxf(mold, mx);
                float alpha = __expf(mold - mnew);
                float rsum = 0.0f;
                #pragma unroll
                for (int nt = 0; nt < 4; ++nt) {
                    float p = __expf(s[mt][nt][r] - mnew);
                    s[mt][nt][r] = p;
                    rsum += p;
                }
                #pragma unroll
                for (int off = 1; off < 16; off <<= 1)
                    rsum += __shfl_xor(rsum, off, 64);
                l_i[mt][r] = alpha * l_i[mt][r] + rsum;
                m_i[mt][r] = mnew;
                #pragma unroll
                for (int nt = 0; nt < 4; ++nt) o[mt][nt][r] *= alpha;
            }
        }

        // ---- P: C/D layout -> LDS -> A layout (f16) ----
        #pragma unroll
        for (int mt = 0; mt < 2; ++mt)
            #pragma unroll
            for (int nt = 0; nt < 4; ++nt)
                #pragma unroll
                for (int r = 0; r < 4; ++r)
                    Pb[wave][mt*16 + quad*4 + r][nt*16 + l15] = (_Float16)s[mt][nt][r];

        // ---- O += P V ----
        #pragma unroll
        for (int kc = 0; kc < 2; ++kc) {
            half8 pa0 = *(const half8*)&Pb[wave][l15][kc*32 + quad*8];
            half8 pa1 = *(const half8*)&Pb[wave][16 + l15][kc*32 + quad*8];
            #pragma unroll
            for (int nt = 0; nt < 4; ++nt) {
                half8 vb = *(const half8*)&Vt[nt*16 + l15][kc*32 + quad*8];
                o[0][nt] = __builtin_amdgcn_mfma_f32_16x16x32_f16(pa0, vb, o[0][nt], 0, 0, 0);
                o[1][nt] = __builtin_amdgcn_mfma_f32_16x16x32_f16(pa1, vb, o[1][nt], 0, 0, 0);
            }
        }
    }

    // ---- epilogue: O / l, fp32 store ----
    #pragma unroll
    for (int mt = 0; mt < 2; ++mt) {
        #pragma unroll
        for (int r = 0; r < 4; ++r) {
            float inv_l = 1.0f / l_i[mt][r];
            int row = q0 + mt*16 + quad*4 + r;
            #pragma unroll
            for (int nt = 0; nt < 4; ++nt)
                Oh[(long)row * DHEAD + nt*16 + l15] = o[mt][nt][r] * inv_l;
        }
    }
}

extern "C" void kernel_launch(void* const* d_in, const int* in_sizes, int n_in,
                              void* d_out, int out_size, void* d_ws, size_t ws_size,
                              hipStream_t stream) {
    const float* Q    = (const float*)d_in[0];
    const float* K    = (const float*)d_in[1];
    const float* V    = (const float*)d_in[2];
    const int*   dk   = (const int*)d_in[3];
    const float* mask = (const float*)d_in[4];
    float* out = (float*)d_out;
    int* flag = (int*)d_ws;

    hipMemsetAsync(flag, 0, sizeof(int), stream);
    mask_flag_kernel<<<1024, 256, 0, stream>>>(mask, flag, (long)S_LEN * S_LEN / 4);

    dim3 grid(S_LEN / BQ, 16);   // 32 q-tiles x (B*H)
    attn_kernel<<<grid, 256, 0, stream>>>(Q, K, V, dk, mask, flag, out);
}

// Round 4
// 354.204 us; speedup vs baseline: 1.0834x; 1.0834x over previous
//
#include <hip/hip_runtime.h>

#define S_LEN 4096
#define DHEAD 64
#define BQ    64       // Q rows per block (4 waves x 16)
#define BK    64       // K/V rows per tile
#define KPAD  72       // halfs; 144 B row stride (16B-aligned)

typedef __fp16   pk16x2 __attribute__((ext_vector_type(2)));  // cvt_pkrtz result
typedef _Float16 half8  __attribute__((ext_vector_type(8)));
typedef float    f32x4  __attribute__((ext_vector_type(4)));

// ---------------------------------------------------------------------------
// Pass 1: is the mask anywhere nonzero? grid-stride, reads 67MB once.
// ---------------------------------------------------------------------------
__global__ void mask_flag_kernel(const float4* __restrict__ mask, int* __restrict__ flag, long n4) {
    long i = (long)blockIdx.x * blockDim.x + threadIdx.x;
    long stride = (long)gridDim.x * blockDim.x;
    int nz = 0;
    for (long j = i; j < n4; j += 4 * stride) {
        long j1 = j + stride, j2 = j + 2 * stride, j3 = j + 3 * stride;
        float4 a = mask[j];
        nz |= (a.x != 0.f) | (a.y != 0.f) | (a.z != 0.f) | (a.w != 0.f);
        if (j1 < n4) { float4 b = mask[j1]; nz |= (b.x != 0.f) | (b.y != 0.f) | (b.z != 0.f) | (b.w != 0.f); }
        if (j2 < n4) { float4 c = mask[j2]; nz |= (c.x != 0.f) | (c.y != 0.f) | (c.z != 0.f) | (c.w != 0.f); }
        if (j3 < n4) { float4 d = mask[j3]; nz |= (d.x != 0.f) | (d.y != 0.f) | (d.z != 0.f) | (d.w != 0.f); }
    }
    if (__any(nz)) {
        if ((threadIdx.x & 63) == 0) atomicOr(flag, 1);
    }
}

// ---------------------------------------------------------------------------
// Pass 2: flash attention, transposed-score trick, ONLY 16x16x32 f16 MFMA
// (round-1-verified layouts).
//   S^T = K·Q^T:  A = K rows (m = k-row), B = Q rows (n = q).
//   C/D of S^T: lane holds q = lane&15, k = quad*4+reg  (per nt block of 16).
//   P -> per-wave LDS buffer (packed b32 writes) -> half8 A-fragment reads.
//   O += P·V:  A = P (m = q), B = V^T from LDS (n = d).
//   O C/D: lane holds q = quad*4+reg, d = dt*16 + (lane&15).
// ---------------------------------------------------------------------------
__global__ __launch_bounds__(256, 4) void attn_kernel(
    const float* __restrict__ Q, const float* __restrict__ K,
    const float* __restrict__ V, const int* __restrict__ dk,
    const float* __restrict__ mask, const int* __restrict__ maskflag,
    float* __restrict__ O)
{
    const int qt   = blockIdx.x;      // 0..63
    const int bh   = blockIdx.y;      // 0..15
    const int tid  = threadIdx.x;
    const int wave = tid >> 6;
    const int lane = tid & 63;
    const int l15  = lane & 15;
    const int quad = lane >> 4;

    const long base = (long)bh * S_LEN * DHEAD;
    const float* Qh = Q + base;
    const float* Kh = K + base;
    const float* Vh = V + base;
    float*       Oh = O + base;

    const int q0 = qt * BQ + wave * 16;            // this wave's 16 q-rows
    const float scale = rsqrtf((float)dk[0]);
    const float cs   = scale * 1.44269504088896f;  // scale * log2(e)
    const float mfac = -1e9f / scale;              // mask folded into raw scores
    const bool use_mask = (maskflag[0] != 0);

    __shared__ __align__(16) _Float16 Kt[BK][KPAD];       // [k-row][d]
    __shared__ __align__(16) _Float16 Vt[DHEAD][KPAD];    // [d][k-row] transposed
    __shared__ __align__(16) _Float16 Pw[4][16][KPAD];    // per-wave P: [q][k]

    // ---- Q fragments (B-operand layout): lane holds q=q0+l15, d=kc*32+quad*8+j
    half8 qf[2];
    #pragma unroll
    for (int kc = 0; kc < 2; ++kc) {
        const float4* src = (const float4*)(Qh + (long)(q0 + l15) * DHEAD + kc*32 + quad*8);
        float4 a = src[0], b = src[1];
        half8 h;
        h[0]=(_Float16)a.x; h[1]=(_Float16)a.y; h[2]=(_Float16)a.z; h[3]=(_Float16)a.w;
        h[4]=(_Float16)b.x; h[5]=(_Float16)b.y; h[6]=(_Float16)b.z; h[7]=(_Float16)b.w;
        qf[kc] = h;
    }

    f32x4 o[4];                 // O accum: lane holds q=quad*4+r, d=dt*16+l15
    #pragma unroll
    for (int dt = 0; dt < 4; ++dt) o[dt] = (f32x4){0.f, 0.f, 0.f, 0.f};
    float m_i = -INFINITY;      // per-lane state for q = q0 + l15 (raw-score units)
    float l_i = 0.0f;

    for (int kt = 0; kt < S_LEN / BK; ++kt) {
        __syncthreads();
        // ---- stage K rows (half8 writes) ----
        {
            const int r   = tid >> 2;   // 0..63 k-row
            const int seg = tid & 3;    // 16-float d-segment
            const float4* k4 = (const float4*)(Kh + (long)(kt*BK + r) * DHEAD + seg*16);
            float4 x0 = k4[0], x1 = k4[1], x2 = k4[2], x3 = k4[3];
            half8 h0, h1;
            h0[0]=(_Float16)x0.x; h0[1]=(_Float16)x0.y; h0[2]=(_Float16)x0.z; h0[3]=(_Float16)x0.w;
            h0[4]=(_Float16)x1.x; h0[5]=(_Float16)x1.y; h0[6]=(_Float16)x1.z; h0[7]=(_Float16)x1.w;
            h1[0]=(_Float16)x2.x; h1[1]=(_Float16)x2.y; h1[2]=(_Float16)x2.z; h1[3]=(_Float16)x2.w;
            h1[4]=(_Float16)x3.x; h1[5]=(_Float16)x3.y; h1[6]=(_Float16)x3.z; h1[7]=(_Float16)x3.w;
            *(half8*)&Kt[r][seg*16]     = h0;
            *(half8*)&Kt[r][seg*16 + 8] = h1;
        }
        // ---- stage V transposed: thread packs half2 of (row 2rp, row 2rp+1) ----
        {
            const int rp = tid >> 3;    // 0..31 row pair
            const int dq = tid & 7;     // d-range dq*8 .. dq*8+7
            const float* v0p = Vh + (long)(kt*BK + 2*rp) * DHEAD + dq*8;
            float4 a0 = ((const float4*)v0p)[0];
            float4 a1 = ((const float4*)v0p)[1];
            const float* v1p = v0p + DHEAD;
            float4 b0 = ((const float4*)v1p)[0];
            float4 b1 = ((const float4*)v1p)[1];
            const int d0 = dq*8, rr = 2*rp;
            *(pk16x2*)&Vt[d0+0][rr] = __builtin_amdgcn_cvt_pkrtz(a0.x, b0.x);
            *(pk16x2*)&Vt[d0+1][rr] = __builtin_amdgcn_cvt_pkrtz(a0.y, b0.y);
            *(pk16x2*)&Vt[d0+2][rr] = __builtin_amdgcn_cvt_pkrtz(a0.z, b0.z);
            *(pk16x2*)&Vt[d0+3][rr] = __builtin_amdgcn_cvt_pkrtz(a0.w, b0.w);
            *(pk16x2*)&Vt[d0+4][rr] = __builtin_amdgcn_cvt_pkrtz(a1.x, b1.x);
            *(pk16x2*)&Vt[d0+5][rr] = __builtin_amdgcn_cvt_pkrtz(a1.y, b1.y);
            *(pk16x2*)&Vt[d0+6][rr] = __builtin_amdgcn_cvt_pkrtz(a1.z, b1.z);
            *(pk16x2*)&Vt[d0+7][rr] = __builtin_amdgcn_cvt_pkrtz(a1.w, b1.w);
        }
        __syncthreads();

        // ---- S^T = K · Q^T : lane holds q=q0+l15, k = kt*64 + nt*16 + quad*4 + r
        f32x4 st[4];
        #pragma unroll
        for (int nt = 0; nt < 4; ++nt) st[nt] = (f32x4){0.f,0.f,0.f,0.f};
        #pragma unroll
        for (int nt = 0; nt < 4; ++nt) {
            #pragma unroll
            for (int kc = 0; kc < 2; ++kc) {
                half8 af = *(const half8*)&Kt[nt*16 + l15][kc*32 + quad*8];
                st[nt] = __builtin_amdgcn_mfma_f32_16x16x32_f16(af, qf[kc], st[nt], 0, 0, 0);
            }
        }

        if (use_mask) {
            const long mrow = (long)(q0 + l15) * S_LEN + kt*BK;
            #pragma unroll
            for (int nt = 0; nt < 4; ++nt)
                #pragma unroll
                for (int r = 0; r < 4; ++r)
                    st[nt][r] += mfac * mask[mrow + nt*16 + quad*4 + r];
        }

        // ---- online softmax (per-lane q; 16 in-lane + 2 cross-quad shfl) ----
        float mx = fmaxf(fmaxf(fmaxf(st[0][0], st[0][1]), fmaxf(st[0][2], st[0][3])),
                         fmaxf(fmaxf(st[1][0], st[1][1]), fmaxf(st[1][2], st[1][3])));
        float mx2 = fmaxf(fmaxf(fmaxf(st[2][0], st[2][1]), fmaxf(st[2][2], st[2][3])),
                          fmaxf(fmaxf(st[3][0], st[3][1]), fmaxf(st[3][2], st[3][3])));
        mx = fmaxf(mx, mx2);
        mx = fmaxf(mx, __shfl_xor(mx, 16, 64));
        mx = fmaxf(mx, __shfl_xor(mx, 32, 64));
        float mnew = fmaxf(m_i, mx);
        float bshift = mnew * cs;
        float rsum = 0.0f;
        #pragma unroll
        for (int nt = 0; nt < 4; ++nt) {
            #pragma unroll
            for (int r = 0; r < 4; ++r) {
                float p = __builtin_amdgcn_exp2f(st[nt][r] * cs - bshift);
                st[nt][r] = p;
                rsum += p;
            }
        }
        rsum += __shfl_xor(rsum, 16, 64);
        rsum += __shfl_xor(rsum, 32, 64);
        float alpha = __builtin_amdgcn_exp2f((m_i - mnew) * cs);
        l_i = alpha * l_i + rsum;
        m_i = mnew;

        // ---- rescale O by alpha of ITS q (q = quad*4+r) ----
        #pragma unroll
        for (int r = 0; r < 4; ++r) {
            float a_r = __shfl(alpha, quad*4 + r, 64);
            #pragma unroll
            for (int dt = 0; dt < 4; ++dt) o[dt][r] *= a_r;
        }

        // ---- P -> per-wave LDS (packed b32), then A-fragment half8 reads ----
        #pragma unroll
        for (int nt = 0; nt < 4; ++nt) {
            *(pk16x2*)&Pw[wave][l15][nt*16 + quad*4]     = __builtin_amdgcn_cvt_pkrtz(st[nt][0], st[nt][1]);
            *(pk16x2*)&Pw[wave][l15][nt*16 + quad*4 + 2] = __builtin_amdgcn_cvt_pkrtz(st[nt][2], st[nt][3]);
        }
        // ---- O += P·V  (A = P: m=q=l15, k=kc2*32+quad*8+j; B = V^T: n=d) ----
        #pragma unroll
        for (int kc2 = 0; kc2 < 2; ++kc2) {
            half8 pa = *(const half8*)&Pw[wave][l15][kc2*32 + quad*8];
            #pragma unroll
            for (int dt = 0; dt < 4; ++dt) {
                half8 vb = *(const half8*)&Vt[dt*16 + l15][kc2*32 + quad*8];
                o[dt] = __builtin_amdgcn_mfma_f32_16x16x32_f16(pa, vb, o[dt], 0, 0, 0);
            }
        }
    }

    // ---- epilogue: O /= l  (l lives on lanes l15=q; broadcast to q=quad*4+r)
    float linv[4];
    #pragma unroll
    for (int r = 0; r < 4; ++r) {
        float lq = __shfl(l_i, quad*4 + r, 64);
        linv[r] = __builtin_amdgcn_rcpf(lq);
    }
    #pragma unroll
    for (int r = 0; r < 4; ++r) {
        const long row = (long)(q0 + quad*4 + r) * DHEAD;
        #pragma unroll
        for (int dt = 0; dt < 4; ++dt)
            Oh[row + dt*16 + l15] = o[dt][r] * linv[r];
    }
}

extern "C" void kernel_launch(void* const* d_in, const int* in_sizes, int n_in,
                              void* d_out, int out_size, void* d_ws, size_t ws_size,
                              hipStream_t stream) {
    const float* Q    = (const float*)d_in[0];
    const float* K    = (const float*)d_in[1];
    const float* V    = (const float*)d_in[2];
    const int*   dk   = (const int*)d_in[3];
    const float* mask = (const float*)d_in[4];
    float* out = (float*)d_out;
    int* flag = (int*)d_ws;

    (void)hipMemsetAsync(flag, 0, sizeof(int), stream);
    mask_flag_kernel<<<2048, 256, 0, stream>>>((const float4*)mask, flag, (long)S_LEN * S_LEN / 4);

    dim3 grid(S_LEN / BQ, 16);   // 64 q-tiles x (B*H) = 1024 blocks
    attn_kernel<<<grid, 256, 0, stream>>>(Q, K, V, dk, mask, flag, out);
}

// Round 5
// 283.845 us; speedup vs baseline: 1.3520x; 1.2479x over previous
//
#include <hip/hip_runtime.h>

#define S_LEN 4096
#define DHEAD 64
#define BQ    64       // Q rows per block (4 waves x 16)
#define BK    64       // K/V rows per tile
#define KPAD  72       // halfs; 144 B row stride (16B-aligned)

typedef __fp16   pk16x2 __attribute__((ext_vector_type(2)));  // cvt_pkrtz result
typedef _Float16 half4v __attribute__((ext_vector_type(4)));
typedef _Float16 half8  __attribute__((ext_vector_type(8)));
typedef float    f32x4  __attribute__((ext_vector_type(4)));

// ---------------------------------------------------------------------------
// Pass 1: is the mask anywhere nonzero? 2048x256 threads, exactly 8 float4
// per thread, branch-free coalesced stride loop.
// ---------------------------------------------------------------------------
__global__ void mask_flag_kernel(const float4* __restrict__ mask, int* __restrict__ flag) {
    const long stride = 2048L * 256;
    long i = (long)blockIdx.x * 256 + threadIdx.x;
    int nz = 0;
    #pragma unroll
    for (int it = 0; it < 8; ++it) {
        float4 a = mask[i + it * stride];
        nz |= (a.x != 0.f) | (a.y != 0.f) | (a.z != 0.f) | (a.w != 0.f);
    }
    if (__any(nz)) {
        if ((threadIdx.x & 63) == 0) atomicOr(flag, 1);
    }
}

// ---------------------------------------------------------------------------
// Pass 2: flash attention, transposed-score trick, 16x16x32 f16 MFMA only.
//   S^T = K·Q^T (Q pre-scaled by scale*log2e; softmax in exp2 domain).
//   V^T LDS layout XOR-swizzled: element (d,r) lives at column block
//   (r>>3)^(d>>3) -> conflict-free staging writes, balanced b128 reads.
//   Register prefetch of next K/V tile overlaps global latency with compute.
// ---------------------------------------------------------------------------
__global__ __launch_bounds__(256, 4) void attn_kernel(
    const float* __restrict__ Q, const float* __restrict__ K,
    const float* __restrict__ V, const int* __restrict__ dk,
    const float* __restrict__ mask, const int* __restrict__ maskflag,
    float* __restrict__ O)
{
    const int qt   = blockIdx.x;      // 0..63
    const int bh   = blockIdx.y;      // 0..15
    const int tid  = threadIdx.x;
    const int wave = tid >> 6;
    const int lane = tid & 63;
    const int l15  = lane & 15;
    const int quad = lane >> 4;

    const long base = (long)bh * S_LEN * DHEAD;
    const float* Qh = Q + base;
    const float* Kh = K + base;
    const float* Vh = V + base;
    float*       Oh = O + base;

    const int q0 = qt * BQ + wave * 16;
    const float csq  = rsqrtf((float)dk[0]) * 1.44269504088896f; // scale*log2(e)
    const float mfac = -1e9f * 1.44269504088896f;                // mask in exp2 domain
    const bool use_mask = (maskflag[0] != 0);

    __shared__ __align__(16) _Float16 Kt[BK][KPAD];        // [k-row][d]
    __shared__ __align__(16) _Float16 Vt[DHEAD * KPAD];    // [d][r], r-blocks XOR-swizzled
    __shared__ __align__(16) _Float16 Pw[4][16][KPAD];     // per-wave P: [q][k]

    // ---- Q fragments (B-operand layout), pre-scaled by scale*log2e ----
    half8 qf[2];
    #pragma unroll
    for (int kc = 0; kc < 2; ++kc) {
        const float4* src = (const float4*)(Qh + (long)(q0 + l15) * DHEAD + kc*32 + quad*8);
        float4 a = src[0], b = src[1];
        union { pk16x2 p[4]; half8 h; } u;
        u.p[0] = __builtin_amdgcn_cvt_pkrtz(a.x*csq, a.y*csq);
        u.p[1] = __builtin_amdgcn_cvt_pkrtz(a.z*csq, a.w*csq);
        u.p[2] = __builtin_amdgcn_cvt_pkrtz(b.x*csq, b.y*csq);
        u.p[3] = __builtin_amdgcn_cvt_pkrtz(b.z*csq, b.w*csq);
        qf[kc] = u.h;
    }

    // ---- staging thread roles + prefetch registers ----
    const int kr  = tid >> 2;            // K: row 0..63
    const int ks  = tid & 3;             // K: 16-float segment
    const int vrp = tid >> 3;            // V: row-pair 0..31
    const int vdq = tid & 7;             // V: d-octet 0..7
    const float* Kb = Kh + (long)kr * DHEAD + ks * 16;
    const float* Vb = Vh + (long)(2 * vrp) * DHEAD + vdq * 8;
    const int vcol = (((vrp >> 2) ^ vdq) << 3) + ((2 * vrp) & 7);  // swizzled col
    const int vd0  = vdq * 8;

    float4 kf[4], vf[4];
    auto load_tile = [&](int kt) {
        const float4* kp  = (const float4*)(Kb + (long)kt * BK * DHEAD);
        kf[0] = kp[0]; kf[1] = kp[1]; kf[2] = kp[2]; kf[3] = kp[3];
        const float4* vp0 = (const float4*)(Vb + (long)kt * BK * DHEAD);
        const float4* vp1 = (const float4*)(Vb + (long)kt * BK * DHEAD + DHEAD);
        vf[0] = vp0[0]; vf[1] = vp0[1]; vf[2] = vp1[0]; vf[3] = vp1[1];
    };
    auto store_tile = [&]() {
        union { pk16x2 p[4]; half8 h; } u0, u1;
        u0.p[0] = __builtin_amdgcn_cvt_pkrtz(kf[0].x, kf[0].y);
        u0.p[1] = __builtin_amdgcn_cvt_pkrtz(kf[0].z, kf[0].w);
        u0.p[2] = __builtin_amdgcn_cvt_pkrtz(kf[1].x, kf[1].y);
        u0.p[3] = __builtin_amdgcn_cvt_pkrtz(kf[1].z, kf[1].w);
        u1.p[0] = __builtin_amdgcn_cvt_pkrtz(kf[2].x, kf[2].y);
        u1.p[1] = __builtin_amdgcn_cvt_pkrtz(kf[2].z, kf[2].w);
        u1.p[2] = __builtin_amdgcn_cvt_pkrtz(kf[3].x, kf[3].y);
        u1.p[3] = __builtin_amdgcn_cvt_pkrtz(kf[3].z, kf[3].w);
        *(half8*)&Kt[kr][ks*16]     = u0.h;
        *(half8*)&Kt[kr][ks*16 + 8] = u1.h;
        // V transposed, swizzled: rows vd0..vd0+7, cols (2vrp, 2vrp+1)
        *(pk16x2*)&Vt[(vd0+0)*KPAD + vcol] = __builtin_amdgcn_cvt_pkrtz(vf[0].x, vf[2].x);
        *(pk16x2*)&Vt[(vd0+1)*KPAD + vcol] = __builtin_amdgcn_cvt_pkrtz(vf[0].y, vf[2].y);
        *(pk16x2*)&Vt[(vd0+2)*KPAD + vcol] = __builtin_amdgcn_cvt_pkrtz(vf[0].z, vf[2].z);
        *(pk16x2*)&Vt[(vd0+3)*KPAD + vcol] = __builtin_amdgcn_cvt_pkrtz(vf[0].w, vf[2].w);
        *(pk16x2*)&Vt[(vd0+4)*KPAD + vcol] = __builtin_amdgcn_cvt_pkrtz(vf[1].x, vf[3].x);
        *(pk16x2*)&Vt[(vd0+5)*KPAD + vcol] = __builtin_amdgcn_cvt_pkrtz(vf[1].y, vf[3].y);
        *(pk16x2*)&Vt[(vd0+6)*KPAD + vcol] = __builtin_amdgcn_cvt_pkrtz(vf[1].z, vf[3].z);
        *(pk16x2*)&Vt[(vd0+7)*KPAD + vcol] = __builtin_amdgcn_cvt_pkrtz(vf[1].w, vf[3].w);
    };

    f32x4 o[4];
    #pragma unroll
    for (int dt = 0; dt < 4; ++dt) o[dt] = (f32x4){0.f, 0.f, 0.f, 0.f};
    float m_i = -INFINITY;   // exp2-domain running max for q = q0 + l15
    float l_i = 0.0f;

    load_tile(0);
    for (int kt = 0; kt < S_LEN / BK; ++kt) {
        store_tile();
        __syncthreads();                       // LDS tile ready
        if (kt + 1 < S_LEN / BK) load_tile(kt + 1);   // prefetch overlaps compute

        // ---- S^T = K · Q^T : lane holds q=q0+l15, k = nt*16 + quad*4 + r ----
        f32x4 st[4];
        #pragma unroll
        for (int nt = 0; nt < 4; ++nt) st[nt] = (f32x4){0.f,0.f,0.f,0.f};
        #pragma unroll
        for (int nt = 0; nt < 4; ++nt) {
            #pragma unroll
            for (int kc = 0; kc < 2; ++kc) {
                half8 af = *(const half8*)&Kt[nt*16 + l15][kc*32 + quad*8];
                st[nt] = __builtin_amdgcn_mfma_f32_16x16x32_f16(af, qf[kc], st[nt], 0, 0, 0);
            }
        }

        if (use_mask) {
            const long mrow = (long)(q0 + l15) * S_LEN + kt*BK;
            #pragma unroll
            for (int nt = 0; nt < 4; ++nt)
                #pragma unroll
                for (int r = 0; r < 4; ++r)
                    st[nt][r] += mfac * mask[mrow + nt*16 + quad*4 + r];
        }

        // ---- online softmax, exp2 domain ----
        float mx = fmaxf(fmaxf(fmaxf(st[0][0], st[0][1]), fmaxf(st[0][2], st[0][3])),
                         fmaxf(fmaxf(st[1][0], st[1][1]), fmaxf(st[1][2], st[1][3])));
        float mx2 = fmaxf(fmaxf(fmaxf(st[2][0], st[2][1]), fmaxf(st[2][2], st[2][3])),
                          fmaxf(fmaxf(st[3][0], st[3][1]), fmaxf(st[3][2], st[3][3])));
        mx = fmaxf(mx, mx2);
        mx = fmaxf(mx, __shfl_xor(mx, 16, 64));
        mx = fmaxf(mx, __shfl_xor(mx, 32, 64));
        float mnew = fmaxf(m_i, mx);
        float rsum = 0.0f;
        #pragma unroll
        for (int nt = 0; nt < 4; ++nt) {
            #pragma unroll
            for (int r = 0; r < 4; ++r) {
                float p = __builtin_amdgcn_exp2f(st[nt][r] - mnew);
                st[nt][r] = p;
                rsum += p;
            }
        }
        rsum += __shfl_xor(rsum, 16, 64);
        rsum += __shfl_xor(rsum, 32, 64);
        float alpha = __builtin_amdgcn_exp2f(m_i - mnew);
        l_i = alpha * l_i + rsum;
        m_i = mnew;

        // ---- rescale O by alpha of ITS q (q = quad*4+r) ----
        #pragma unroll
        for (int r = 0; r < 4; ++r) {
            float a_r = __shfl(alpha, quad*4 + r, 64);
            #pragma unroll
            for (int dt = 0; dt < 4; ++dt) o[dt][r] *= a_r;
        }

        // ---- P -> per-wave LDS (b64 writes), then half8 A-fragment reads ----
        #pragma unroll
        for (int nt = 0; nt < 4; ++nt) {
            union { pk16x2 p[2]; half4v h; } up;
            up.p[0] = __builtin_amdgcn_cvt_pkrtz(st[nt][0], st[nt][1]);
            up.p[1] = __builtin_amdgcn_cvt_pkrtz(st[nt][2], st[nt][3]);
            *(half4v*)&Pw[wave][l15][nt*16 + quad*4] = up.h;
        }
        // ---- O += P·V  (A = P: m=q=l15; B = V^T swizzled: n=d) ----
        #pragma unroll
        for (int kc2 = 0; kc2 < 2; ++kc2) {
            half8 pa = *(const half8*)&Pw[wave][l15][kc2*32 + quad*8];
            #pragma unroll
            for (int dt = 0; dt < 4; ++dt) {
                const int row = dt*16 + l15;
                const int pb  = (4*kc2 + quad) ^ (row >> 3);   // swizzled block
                half8 vb = *(const half8*)&Vt[row*KPAD + pb*8];
                o[dt] = __builtin_amdgcn_mfma_f32_16x16x32_f16(pa, vb, o[dt], 0, 0, 0);
            }
        }
        __syncthreads();                       // all waves done reading LDS
    }

    // ---- epilogue: O /= l ----
    float linv[4];
    #pragma unroll
    for (int r = 0; r < 4; ++r) {
        float lq = __shfl(l_i, quad*4 + r, 64);
        linv[r] = __builtin_amdgcn_rcpf(lq);
    }
    #pragma unroll
    for (int r = 0; r < 4; ++r) {
        const long row = (long)(q0 + quad*4 + r) * DHEAD;
        #pragma unroll
        for (int dt = 0; dt < 4; ++dt)
            Oh[row + dt*16 + l15] = o[dt][r] * linv[r];
    }
}

extern "C" void kernel_launch(void* const* d_in, const int* in_sizes, int n_in,
                              void* d_out, int out_size, void* d_ws, size_t ws_size,
                              hipStream_t stream) {
    const float* Q    = (const float*)d_in[0];
    const float* K    = (const float*)d_in[1];
    const float* V    = (const float*)d_in[2];
    const int*   dk   = (const int*)d_in[3];
    const float* mask = (const float*)d_in[4];
    float* out = (float*)d_out;
    int* flag = (int*)d_ws;

    (void)hipMemsetAsync(flag, 0, sizeof(int), stream);
    mask_flag_kernel<<<2048, 256, 0, stream>>>((const float4*)mask, flag);

    dim3 grid(S_LEN / BQ, 16);   // 64 q-tiles x (B*H) = 1024 blocks
    attn_kernel<<<grid, 256, 0, stream>>>(Q, K, V, dk, mask, flag, out);
}

// Round 6
// 258.106 us; speedup vs baseline: 1.4868x; 1.0997x over previous
//
#include <hip/hip_runtime.h>

#define S_LEN 4096
#define DHEAD 64
#define BQ    128      // Q rows per block (4 waves x 32)
#define BK    64       // K/V rows per tile
#define NT    (S_LEN / BK)
#define KPAD  72       // halfs; 144 B row stride (16B-aligned)

typedef __fp16   pk16x2 __attribute__((ext_vector_type(2)));  // cvt_pkrtz result
typedef _Float16 half4v __attribute__((ext_vector_type(4)));
typedef _Float16 half8  __attribute__((ext_vector_type(8)));
typedef float    f32x4  __attribute__((ext_vector_type(4)));

// ---------------------------------------------------------------------------
// Pass 1: is the mask anywhere nonzero? 2048x256 threads, 8 float4/thread.
// ---------------------------------------------------------------------------
__global__ void mask_flag_kernel(const float4* __restrict__ mask, int* __restrict__ flag) {
    const long stride = 2048L * 256;
    long i = (long)blockIdx.x * 256 + threadIdx.x;
    int nz = 0;
    #pragma unroll
    for (int it = 0; it < 8; ++it) {
        float4 a = mask[i + it * stride];
        nz |= (a.x != 0.f) | (a.y != 0.f) | (a.z != 0.f) | (a.w != 0.f);
    }
    if (__any(nz)) {
        if ((threadIdx.x & 63) == 0) atomicOr(flag, 1);
    }
}

// ---------------------------------------------------------------------------
// Pass 2: flash attention, transposed-score trick, WQ=32 (two Q fragments per
// wave -> K/V fragment LDS reads amortized over 2x MFMAs), LDS double buffer
// (one barrier per K-tile).
// ---------------------------------------------------------------------------
__global__ __launch_bounds__(256, 2) void attn_kernel(
    const float* __restrict__ Q, const float* __restrict__ K,
    const float* __restrict__ V, const int* __restrict__ dk,
    const float* __restrict__ mask, const int* __restrict__ maskflag,
    float* __restrict__ O)
{
    const int qt   = blockIdx.x;      // 0..31
    const int bh   = blockIdx.y;      // 0..15
    const int tid  = threadIdx.x;
    const int wave = tid >> 6;
    const int lane = tid & 63;
    const int l15  = lane & 15;
    const int quad = lane >> 4;

    const long base = (long)bh * S_LEN * DHEAD;
    const float* Qh = Q + base;
    const float* Kh = K + base;
    const float* Vh = V + base;
    float*       Oh = O + base;

    const int q0 = qt * BQ + wave * 32;            // this wave's 32 q-rows
    const float csq  = rsqrtf((float)dk[0]) * 1.44269504088896f; // scale*log2(e)
    const float mfac = -1e9f * 1.44269504088896f;                // exp2 domain
    const bool use_mask = (maskflag[0] != 0);

    __shared__ __align__(16) _Float16 Kt[2][BK][KPAD];      // [buf][k-row][d]
    __shared__ __align__(16) _Float16 Vt[2][DHEAD * KPAD];  // [buf][d][r] swizzled
    __shared__ __align__(16) _Float16 Pw[4][32][KPAD];      // per-wave P: [q][k]

    // ---- Q fragments (B-operand layout), pre-scaled; 2 frags of 16 rows ----
    half8 qf[2][2];
    #pragma unroll
    for (int f = 0; f < 2; ++f) {
        #pragma unroll
        for (int kc = 0; kc < 2; ++kc) {
            const float4* src = (const float4*)(Qh + (long)(q0 + f*16 + l15) * DHEAD + kc*32 + quad*8);
            float4 a = src[0], b = src[1];
            union { pk16x2 p[4]; half8 h; } u;
            u.p[0] = __builtin_amdgcn_cvt_pkrtz(a.x*csq, a.y*csq);
            u.p[1] = __builtin_amdgcn_cvt_pkrtz(a.z*csq, a.w*csq);
            u.p[2] = __builtin_amdgcn_cvt_pkrtz(b.x*csq, b.y*csq);
            u.p[3] = __builtin_amdgcn_cvt_pkrtz(b.z*csq, b.w*csq);
            qf[f][kc] = u.h;
        }
    }

    // ---- staging roles + prefetch registers ----
    const int kr  = tid >> 2;            // K: row 0..63
    const int ks  = tid & 3;             // K: 16-float segment
    const int vrp = tid >> 3;            // V: row-pair 0..31
    const int vdq = tid & 7;             // V: d-octet 0..7
    const float* Kb = Kh + (long)kr * DHEAD + ks * 16;
    const float* Vb = Vh + (long)(2 * vrp) * DHEAD + vdq * 8;
    const int vcol = (((vrp >> 2) ^ vdq) << 3) + ((2 * vrp) & 7);  // swizzled col
    const int vd0  = vdq * 8;

    float4 kf[4], vf[4];
    auto load_tile = [&](int kt) {
        const float4* kp  = (const float4*)(Kb + (long)kt * BK * DHEAD);
        kf[0] = kp[0]; kf[1] = kp[1]; kf[2] = kp[2]; kf[3] = kp[3];
        const float4* vp0 = (const float4*)(Vb + (long)kt * BK * DHEAD);
        const float4* vp1 = (const float4*)(Vb + (long)kt * BK * DHEAD + DHEAD);
        vf[0] = vp0[0]; vf[1] = vp0[1]; vf[2] = vp1[0]; vf[3] = vp1[1];
    };
    auto store_tile = [&](int b) {
        union { pk16x2 p[4]; half8 h; } u0, u1;
        u0.p[0] = __builtin_amdgcn_cvt_pkrtz(kf[0].x, kf[0].y);
        u0.p[1] = __builtin_amdgcn_cvt_pkrtz(kf[0].z, kf[0].w);
        u0.p[2] = __builtin_amdgcn_cvt_pkrtz(kf[1].x, kf[1].y);
        u0.p[3] = __builtin_amdgcn_cvt_pkrtz(kf[1].z, kf[1].w);
        u1.p[0] = __builtin_amdgcn_cvt_pkrtz(kf[2].x, kf[2].y);
        u1.p[1] = __builtin_amdgcn_cvt_pkrtz(kf[2].z, kf[2].w);
        u1.p[2] = __builtin_amdgcn_cvt_pkrtz(kf[3].x, kf[3].y);
        u1.p[3] = __builtin_amdgcn_cvt_pkrtz(kf[3].z, kf[3].w);
        *(half8*)&Kt[b][kr][ks*16]     = u0.h;
        *(half8*)&Kt[b][kr][ks*16 + 8] = u1.h;
        _Float16* vt = &Vt[b][0];
        *(pk16x2*)&vt[(vd0+0)*KPAD + vcol] = __builtin_amdgcn_cvt_pkrtz(vf[0].x, vf[2].x);
        *(pk16x2*)&vt[(vd0+1)*KPAD + vcol] = __builtin_amdgcn_cvt_pkrtz(vf[0].y, vf[2].y);
        *(pk16x2*)&vt[(vd0+2)*KPAD + vcol] = __builtin_amdgcn_cvt_pkrtz(vf[0].z, vf[2].z);
        *(pk16x2*)&vt[(vd0+3)*KPAD + vcol] = __builtin_amdgcn_cvt_pkrtz(vf[0].w, vf[2].w);
        *(pk16x2*)&vt[(vd0+4)*KPAD + vcol] = __builtin_amdgcn_cvt_pkrtz(vf[1].x, vf[3].x);
        *(pk16x2*)&vt[(vd0+5)*KPAD + vcol] = __builtin_amdgcn_cvt_pkrtz(vf[1].y, vf[3].y);
        *(pk16x2*)&vt[(vd0+6)*KPAD + vcol] = __builtin_amdgcn_cvt_pkrtz(vf[1].z, vf[3].z);
        *(pk16x2*)&vt[(vd0+7)*KPAD + vcol] = __builtin_amdgcn_cvt_pkrtz(vf[1].w, vf[3].w);
    };

    f32x4 o[2][4];
    #pragma unroll
    for (int f = 0; f < 2; ++f)
        #pragma unroll
        for (int dt = 0; dt < 4; ++dt) o[f][dt] = (f32x4){0.f, 0.f, 0.f, 0.f};
    float m_i[2] = {-INFINITY, -INFINITY};
    float l_i[2] = {0.0f, 0.0f};

    load_tile(0);
    store_tile(0);
    __syncthreads();

    for (int kt = 0; kt < NT; ++kt) {
        const int b = kt & 1;
        if (kt + 1 < NT) load_tile(kt + 1);    // global prefetch overlaps compute

        // ---- S^T = K · Q^T for both frags (K-frag reads shared) ----
        f32x4 st[2][4];
        #pragma unroll
        for (int f = 0; f < 2; ++f)
            #pragma unroll
            for (int nt = 0; nt < 4; ++nt) st[f][nt] = (f32x4){0.f,0.f,0.f,0.f};
        #pragma unroll
        for (int nt = 0; nt < 4; ++nt) {
            #pragma unroll
            for (int kc = 0; kc < 2; ++kc) {
                half8 af = *(const half8*)&Kt[b][nt*16 + l15][kc*32 + quad*8];
                st[0][nt] = __builtin_amdgcn_mfma_f32_16x16x32_f16(af, qf[0][kc], st[0][nt], 0, 0, 0);
                st[1][nt] = __builtin_amdgcn_mfma_f32_16x16x32_f16(af, qf[1][kc], st[1][nt], 0, 0, 0);
            }
        }

        if (use_mask) {
            #pragma unroll
            for (int f = 0; f < 2; ++f) {
                const long mrow = (long)(q0 + f*16 + l15) * S_LEN + kt*BK;
                #pragma unroll
                for (int nt = 0; nt < 4; ++nt)
                    #pragma unroll
                    for (int r = 0; r < 4; ++r)
                        st[f][nt][r] += mfac * mask[mrow + nt*16 + quad*4 + r];
            }
        }

        // ---- online softmax (exp2 domain), per frag ----
        float alpha[2];
        #pragma unroll
        for (int f = 0; f < 2; ++f) {
            float mx = fmaxf(fmaxf(fmaxf(st[f][0][0], st[f][0][1]), fmaxf(st[f][0][2], st[f][0][3])),
                             fmaxf(fmaxf(st[f][1][0], st[f][1][1]), fmaxf(st[f][1][2], st[f][1][3])));
            float mx2 = fmaxf(fmaxf(fmaxf(st[f][2][0], st[f][2][1]), fmaxf(st[f][2][2], st[f][2][3])),
                              fmaxf(fmaxf(st[f][3][0], st[f][3][1]), fmaxf(st[f][3][2], st[f][3][3])));
            mx = fmaxf(mx, mx2);
            mx = fmaxf(mx, __shfl_xor(mx, 16, 64));
            mx = fmaxf(mx, __shfl_xor(mx, 32, 64));
            float mnew = fmaxf(m_i[f], mx);
            float rsum = 0.0f;
            #pragma unroll
            for (int nt = 0; nt < 4; ++nt) {
                #pragma unroll
                for (int r = 0; r < 4; ++r) {
                    float p = __builtin_amdgcn_exp2f(st[f][nt][r] - mnew);
                    st[f][nt][r] = p;
                    rsum += p;
                }
            }
            rsum += __shfl_xor(rsum, 16, 64);
            rsum += __shfl_xor(rsum, 32, 64);
            alpha[f] = __builtin_amdgcn_exp2f(m_i[f] - mnew);
            l_i[f] = alpha[f] * l_i[f] + rsum;
            m_i[f] = mnew;
        }

        // ---- rescale O ----
        #pragma unroll
        for (int f = 0; f < 2; ++f)
            #pragma unroll
            for (int r = 0; r < 4; ++r) {
                float a_r = __shfl(alpha[f], quad*4 + r, 64);
                #pragma unroll
                for (int dt = 0; dt < 4; ++dt) o[f][dt][r] *= a_r;
            }

        // ---- P -> per-wave LDS (b64 writes) ----
        #pragma unroll
        for (int f = 0; f < 2; ++f)
            #pragma unroll
            for (int nt = 0; nt < 4; ++nt) {
                union { pk16x2 p[2]; half4v h; } up;
                up.p[0] = __builtin_amdgcn_cvt_pkrtz(st[f][nt][0], st[f][nt][1]);
                up.p[1] = __builtin_amdgcn_cvt_pkrtz(st[f][nt][2], st[f][nt][3]);
                *(half4v*)&Pw[wave][f*16 + l15][nt*16 + quad*4] = up.h;
            }

        // ---- O += P·V  (V-frag reads shared across frags) ----
        #pragma unroll
        for (int kc2 = 0; kc2 < 2; ++kc2) {
            half8 pa0 = *(const half8*)&Pw[wave][l15][kc2*32 + quad*8];
            half8 pa1 = *(const half8*)&Pw[wave][16 + l15][kc2*32 + quad*8];
            #pragma unroll
            for (int dt = 0; dt < 4; ++dt) {
                const int row = dt*16 + l15;
                const int pb  = (4*kc2 + quad) ^ (row >> 3);
                half8 vb = *(const half8*)&Vt[b][row*KPAD + pb*8];
                o[0][dt] = __builtin_amdgcn_mfma_f32_16x16x32_f16(pa0, vb, o[0][dt], 0, 0, 0);
                o[1][dt] = __builtin_amdgcn_mfma_f32_16x16x32_f16(pa1, vb, o[1][dt], 0, 0, 0);
            }
        }

        if (kt + 1 < NT) {
            store_tile((kt + 1) & 1);   // other buffer; no read hazard
            __syncthreads();            // one barrier per K-tile
        }
    }

    // ---- epilogue: O /= l ----
    #pragma unroll
    for (int f = 0; f < 2; ++f) {
        #pragma unroll
        for (int r = 0; r < 4; ++r) {
            float lq = __shfl(l_i[f], quad*4 + r, 64);
            float linv = __builtin_amdgcn_rcpf(lq);
            const long row = (long)(q0 + f*16 + quad*4 + r) * DHEAD;
            #pragma unroll
            for (int dt = 0; dt < 4; ++dt)
                Oh[row + dt*16 + l15] = o[f][dt][r] * linv;
        }
    }
}

extern "C" void kernel_launch(void* const* d_in, const int* in_sizes, int n_in,
                              void* d_out, int out_size, void* d_ws, size_t ws_size,
                              hipStream_t stream) {
    const float* Q    = (const float*)d_in[0];
    const float* K    = (const float*)d_in[1];
    const float* V    = (const float*)d_in[2];
    const int*   dk   = (const int*)d_in[3];
    const float* mask = (const float*)d_in[4];
    float* out = (float*)d_out;
    int* flag = (int*)d_ws;

    (void)hipMemsetAsync(flag, 0, sizeof(int), stream);
    mask_flag_kernel<<<2048, 256, 0, stream>>>((const float4*)mask, flag);

    dim3 grid(S_LEN / BQ, 16);   // 32 q-tiles x (B*H) = 512 blocks
    attn_kernel<<<grid, 256, 0, stream>>>(Q, K, V, dk, mask, flag, out);
}